// Round 7
// baseline (226.223 us; speedup 1.0000x reference)
//
#include <hip/hip_runtime.h>
#include <math.h>

#define R_RAYS 65536
#define S_SAMP 128
#define NB 4096                 // 8 groups/block * 2 rays/group = 16 rays/block
// out layout: [0]=d_rgb, [1..R]=d_op, [1+R]=d_eik, [2+R .. 1+2R]=d_dist
// ws  layout: [0..NB)=ek partials, [NB..2NB)=rgb partials

typedef float vfloat4 __attribute__((ext_vector_type(4)));
__device__ __forceinline__ float4 nt_load4(const float* p) {
    vfloat4 v = __builtin_nontemporal_load((const vfloat4*)p);
    return make_float4(v.x, v.y, v.z, v.w);
}

template <int CTRL, int ROW_MASK>
__device__ __forceinline__ float dpp_add(float x) {
    int moved = __builtin_amdgcn_update_dpp(0, __float_as_int(x), CTRL, ROW_MASK, 0xF, true);
    return x + __int_as_float(moved);
}

// inclusive scan over each 32-lane half (5 VALU DPP adds)
__device__ __forceinline__ float scan32(float x) {
    x = dpp_add<0x111, 0xF>(x);  // row_shr:1
    x = dpp_add<0x112, 0xF>(x);  // row_shr:2
    x = dpp_add<0x114, 0xF>(x);  // row_shr:4
    x = dpp_add<0x118, 0xF>(x);  // row_shr:8
    x = dpp_add<0x142, 0xA>(x);  // row_bcast:15 (bridge 16->32)
    return x;                    // lane 31 of each half holds the half-total
}

// full-wave reduction; lane 63 ends with the 64-lane total
__device__ __forceinline__ float reduce64(float x) {
    x = dpp_add<0x111, 0xF>(x);
    x = dpp_add<0x112, 0xF>(x);
    x = dpp_add<0x114, 0xF>(x);
    x = dpp_add<0x118, 0xF>(x);
    x = dpp_add<0x142, 0xA>(x);  // row_bcast:15
    x = dpp_add<0x143, 0xC>(x);  // row_bcast:31
    return x;
}

// dist-loss "per" contribution of this lane for one ray's 4 samples,
// given the lane's float4s; scan32 of the return value (done by caller)
// yields the per-ray total in lane 31 of each 32-half.
__device__ __forceinline__ float dist_per(const float4 w4, const float4 t4, const float4 d4) {
    const float wv[4] = { w4.x, w4.y, w4.z, w4.w };
    const float tv[4] = { t4.x, t4.y, t4.z, t4.w };
    const float dv[4] = { d4.x, d4.y, d4.z, d4.w };
    float wtv[4];
    float sw = 0.f, swt = 0.f;
#pragma unroll
    for (int j = 0; j < 4; ++j) { wtv[j] = wv[j] * tv[j]; sw += wv[j]; swt += wtv[j]; }
    const float isw  = scan32(sw);
    const float iswt = scan32(swt);
    float ew  = isw  - sw;
    float ewt = iswt - swt;
    float per = 0.f;
#pragma unroll
    for (int j = 0; j < 4; ++j) {
        per += 2.f * wv[j] * (tv[j] * ew - ewt) + wv[j] * wv[j] * dv[j] * (1.f / 3.f);
        ew  += wv[j];
        ewt += wtv[j];
    }
    return per;
}

__device__ __forceinline__ float eik4(const float4 g0, const float4 g1, const float4 g2) {
    float ek = 0.f, n;
    n = sqrtf(g0.x*g0.x + g0.y*g0.y + g0.z*g0.z); ek += (n-1.f)*(n-1.f);
    n = sqrtf(g0.w*g0.w + g1.x*g1.x + g1.y*g1.y); ek += (n-1.f)*(n-1.f);
    n = sqrtf(g1.z*g1.z + g1.w*g1.w + g2.x*g2.x); ek += (n-1.f)*(n-1.f);
    n = sqrtf(g2.y*g2.y + g2.z*g2.z + g2.w*g2.w); ek += (n-1.f)*(n-1.f);
    return ek;
}

__global__ __launch_bounds__(256) void nerf_main_kernel(
    const float* __restrict__ rgb, const float* __restrict__ tgt,
    const float* __restrict__ opacity, const float* __restrict__ grad,
    const float* __restrict__ ws, const float* __restrict__ deltas,
    const float* __restrict__ ts, const int* __restrict__ rays_a,
    float* __restrict__ out, float* __restrict__ partials)
{
    const int tid  = threadIdx.x;      // 0..255
    const int wave = tid >> 6;         // 0..3
    const int lane = tid & 63;
    const int grp  = tid >> 5;         // 0..7 : 32-lane group == 2 rays
    const int l32  = tid & 31;
    const int b    = blockIdx.x;
    const int r0   = (b * 8 + grp) * 2;          // rays r0, r0+1

    // starts are arange(R)*S by construction
    const int iA = r0 * S_SAMP + l32 * 4;
    const int iB = iA + S_SAMP;

    // ---- 12 independent nt dwordx4 loads per lane, all issued up-front ----
    const float4 wA = nt_load4(ws + iA),     wB = nt_load4(ws + iB);
    const float4 tA = nt_load4(ts + iA),     tB = nt_load4(ts + iB);
    const float4 dA = nt_load4(deltas + iA), dB = nt_load4(deltas + iB);
    const float* gpA = grad + 3 * iA;
    const float* gpB = grad + 3 * iB;
    const float4 g0A = nt_load4(gpA + 0), g1A = nt_load4(gpA + 4), g2A = nt_load4(gpA + 8);
    const float4 g0B = nt_load4(gpB + 0), g1B = nt_load4(gpB + 4), g2B = nt_load4(gpB + 8);
    const int ridx0 = rays_a[3 * r0];
    const int ridx1 = rays_a[3 * r0 + 3];

    // ---- compute both rays ----
    const float perA = scan32(dist_per(wA, tA, dA));   // ray total in lane31 of half
    const float perB = scan32(dist_per(wB, tB, dB));
    float ek = eik4(g0A, g1A, g2A) + eik4(g0B, g1B, g2B);
    const float ek_tot = reduce64(ek);                 // wave total in lane 63

    __shared__ float s_ek[4], s_rg[8];
    if (lane == 63) s_ek[wave] = ek_tot;

    if (l32 == 31) {
        out[2 + R_RAYS + ridx0] = 0.001f * perA;       // L_DIST * per_row
        out[2 + R_RAYS + ridx1] = 0.001f * perB;
    } else if (l32 == 1) {
        const float op0 = opacity[r0], op1 = opacity[r0 + 1];
        out[1 + r0]     = 0.05f * (-op0 * logf(op0));  // L_OP * entropy
        out[1 + r0 + 1] = 0.05f * (-op1 * logf(op1));
    } else if (l32 == 2) {
        float srgb = 0.f;
#pragma unroll
        for (int c = 0; c < 6; ++c) {
            const float diff = fabsf(rgb[3 * r0 + c] - tgt[3 * r0 + c]);
            srgb += (diff < 1.f) ? 0.5f * diff * diff : (diff - 0.5f);
        }
        s_rg[grp] = srgb;
    }
    __syncthreads();

    if (tid == 0) {
        float bek = s_ek[0] + s_ek[1] + s_ek[2] + s_ek[3];
        float brg = 0.f;
#pragma unroll
        for (int j = 0; j < 8; ++j) brg += s_rg[j];
        partials[b]      = bek;
        partials[NB + b] = brg;
    }
}

__global__ __launch_bounds__(1024) void nerf_final_kernel(
    const float* __restrict__ partials, float* __restrict__ out)
{
    const int tid  = threadIdx.x;
    const int lane = tid & 63;
    const int wave = tid >> 6;

    float ek = 0.f, rg = 0.f;
#pragma unroll
    for (int k = 0; k < NB / 1024; ++k) {
        ek += partials[tid + k * 1024];
        rg += partials[NB + tid + k * 1024];
    }
    ek = reduce64(ek);
    rg = reduce64(rg);
    __shared__ float s_ek[16], s_rg[16];
    if (lane == 63) { s_ek[wave] = ek; s_rg[wave] = rg; }
    __syncthreads();
    if (tid == 0) {
        float tek = 0.f, trg = 0.f;
#pragma unroll
        for (int j = 0; j < 16; ++j) { tek += s_ek[j]; trg += s_rg[j]; }
        out[0]          = trg / (3.f * (float)R_RAYS);                    // d_rgb
        out[1 + R_RAYS] = 0.1f * tek / ((float)R_RAYS * (float)S_SAMP);   // d_eik
    }
}

extern "C" void kernel_launch(void* const* d_in, const int* in_sizes, int n_in,
                              void* d_out, int out_size, void* d_ws, size_t ws_size,
                              hipStream_t stream) {
    const float* rgb     = (const float*)d_in[0];
    const float* tgt     = (const float*)d_in[1];
    const float* opacity = (const float*)d_in[2];
    const float* grad    = (const float*)d_in[3];
    const float* ws      = (const float*)d_in[4];
    const float* deltas  = (const float*)d_in[5];
    const float* ts      = (const float*)d_in[6];
    const int*   rays_a  = (const int*)d_in[7];
    float* out      = (float*)d_out;
    float* partials = (float*)d_ws;

    nerf_main_kernel<<<NB, 256, 0, stream>>>(rgb, tgt, opacity, grad, ws,
                                             deltas, ts, rays_a, out, partials);
    nerf_final_kernel<<<1, 1024, 0, stream>>>(partials, out);
}

// Round 8
// 223.313 us; speedup vs baseline: 1.0130x; 1.0130x over previous
//
#include <hip/hip_runtime.h>
#include <math.h>

#define R_RAYS 65536
#define S_SAMP 128
#define NB 8192                 // 8 rays per 256-thr block
// out layout: [0]=d_rgb, [1..R]=d_op, [1+R]=d_eik, [2+R .. 1+2R]=d_dist
// ws  layout: [0..NB)=ek partials, [NB..2NB)=rgb partials

typedef float vfloat4 __attribute__((ext_vector_type(4)));
__device__ __forceinline__ float4 nt_load4(const float* p) {
    vfloat4 v = __builtin_nontemporal_load((const vfloat4*)p);
    return make_float4(v.x, v.y, v.z, v.w);
}

template <int CTRL, int ROW_MASK>
__device__ __forceinline__ float dpp_add(float x) {
    int moved = __builtin_amdgcn_update_dpp(0, __float_as_int(x), CTRL, ROW_MASK, 0xF, true);
    return x + __int_as_float(moved);
}

// inclusive scan over each 32-lane half (5 VALU DPP adds)
__device__ __forceinline__ float scan32(float x) {
    x = dpp_add<0x111, 0xF>(x);  // row_shr:1
    x = dpp_add<0x112, 0xF>(x);  // row_shr:2
    x = dpp_add<0x114, 0xF>(x);  // row_shr:4
    x = dpp_add<0x118, 0xF>(x);  // row_shr:8
    x = dpp_add<0x142, 0xA>(x);  // row_bcast:15 (bridge 16->32)
    return x;                    // lane 31 of each half holds the half-total
}

// full-wave reduction; lane 63 ends with the 64-lane total
__device__ __forceinline__ float reduce64(float x) {
    x = dpp_add<0x111, 0xF>(x);
    x = dpp_add<0x112, 0xF>(x);
    x = dpp_add<0x114, 0xF>(x);
    x = dpp_add<0x118, 0xF>(x);
    x = dpp_add<0x142, 0xA>(x);  // row_bcast:15
    x = dpp_add<0x143, 0xC>(x);  // row_bcast:31
    return x;
}

__global__ __launch_bounds__(256) void nerf_main_kernel(
    const float* __restrict__ rgb, const float* __restrict__ tgt,
    const float* __restrict__ opacity, const float* __restrict__ grad,
    const float* __restrict__ ws, const float* __restrict__ deltas,
    const float* __restrict__ ts, const int* __restrict__ rays_a,
    float* __restrict__ out, float* __restrict__ partials)
{
    const int tid  = threadIdx.x;      // 0..255
    const int wave = tid >> 6;         // 0..3
    const int lane = tid & 63;
    const int grp  = tid >> 5;         // 0..7 : 32-lane group == one ray
    const int l32  = tid & 31;
    const int b    = blockIdx.x;
    const int r    = b * 8 + grp;

    // starts are arange(R)*S by construction -> no load on the address path
    const int i0 = r * S_SAMP + l32 * 4;

    // ---- 6 independent nt dwordx4 loads per lane, issued up-front ----
    // nt bypasses the per-CU L1 miss path: 74 -> <58 us (R5->R6 evidence)
    const float4 w4 = nt_load4(ws + i0);
    const float4 t4 = nt_load4(ts + i0);
    const float4 d4 = nt_load4(deltas + i0);
    const float* gp = grad + 3 * i0;              // 16B aligned (48B/lane)
    const float4 g0 = nt_load4(gp + 0);
    const float4 g1 = nt_load4(gp + 4);
    const float4 g2 = nt_load4(gp + 8);
    const int ridx = rays_a[3 * r];               // off critical path

    const float wv[4] = { w4.x, w4.y, w4.z, w4.w };
    const float tv[4] = { t4.x, t4.y, t4.z, t4.w };
    const float dv[4] = { d4.x, d4.y, d4.z, d4.w };

    float wtv[4];
    float sw = 0.f, swt = 0.f;
#pragma unroll
    for (int j = 0; j < 4; ++j) { wtv[j] = wv[j] * tv[j]; sw += wv[j]; swt += wtv[j]; }

    // ---- ray-local (width-32) inclusive scan via DPP ----
    const float isw  = scan32(sw);
    const float iswt = scan32(swt);
    float ew  = isw  - sw;
    float ewt = iswt - swt;

    float per = 0.f;
#pragma unroll
    for (int j = 0; j < 4; ++j) {
        per += 2.f * wv[j] * (tv[j] * ew - ewt) + wv[j] * wv[j] * dv[j] * (1.f / 3.f);
        ew  += wv[j];
        ewt += wtv[j];
    }

    // ---- eikonal for the 4 grad rows ----
    float ek = 0.f;
    {
        float n;
        n = sqrtf(g0.x*g0.x + g0.y*g0.y + g0.z*g0.z); ek += (n-1.f)*(n-1.f);
        n = sqrtf(g0.w*g0.w + g1.x*g1.x + g1.y*g1.y); ek += (n-1.f)*(n-1.f);
        n = sqrtf(g1.z*g1.z + g1.w*g1.w + g2.x*g2.x); ek += (n-1.f)*(n-1.f);
        n = sqrtf(g2.y*g2.y + g2.z*g2.z + g2.w*g2.w); ek += (n-1.f)*(n-1.f);
    }

    const float per_scan = scan32(per);   // per-ray total lands in lane 31 of each half
    const float ek_tot   = reduce64(ek);  // wave total in lane 63

    __shared__ float s_ek[4], s_rg[8];
    if (lane == 63) s_ek[wave] = ek_tot;

    if (l32 == 31) {
        out[2 + R_RAYS + ridx] = 0.001f * per_scan;              // L_DIST * per_row
    } else if (l32 == 1) {
        const float op = opacity[r];
        out[1 + r] = 0.05f * (-op * logf(op));                   // L_OP * entropy
    } else if (l32 == 2) {
        float srgb = 0.f;
#pragma unroll
        for (int c = 0; c < 3; ++c) {
            const float diff = fabsf(rgb[3 * r + c] - tgt[3 * r + c]);
            srgb += (diff < 1.f) ? 0.5f * diff * diff : (diff - 0.5f);
        }
        s_rg[grp] = srgb;
    }
    __syncthreads();

    if (tid == 0) {
        float bek = s_ek[0] + s_ek[1] + s_ek[2] + s_ek[3];
        float brg = 0.f;
#pragma unroll
        for (int j = 0; j < 8; ++j) brg += s_rg[j];
        partials[b]      = bek;
        partials[NB + b] = brg;
    }
}

__global__ __launch_bounds__(1024) void nerf_final_kernel(
    const float* __restrict__ partials, float* __restrict__ out)
{
    const int tid  = threadIdx.x;
    const int lane = tid & 63;
    const int wave = tid >> 6;

    float ek = 0.f, rg = 0.f;
#pragma unroll
    for (int k = 0; k < NB / 1024; ++k) {
        ek += partials[tid + k * 1024];
        rg += partials[NB + tid + k * 1024];
    }
    ek = reduce64(ek);
    rg = reduce64(rg);
    __shared__ float s_ek[16], s_rg[16];
    if (lane == 63) { s_ek[wave] = ek; s_rg[wave] = rg; }
    __syncthreads();
    if (tid == 0) {
        float tek = 0.f, trg = 0.f;
#pragma unroll
        for (int j = 0; j < 16; ++j) { tek += s_ek[j]; trg += s_rg[j]; }
        out[0]          = trg / (3.f * (float)R_RAYS);                    // d_rgb
        out[1 + R_RAYS] = 0.1f * tek / ((float)R_RAYS * (float)S_SAMP);   // d_eik
    }
}

extern "C" void kernel_launch(void* const* d_in, const int* in_sizes, int n_in,
                              void* d_out, int out_size, void* d_ws, size_t ws_size,
                              hipStream_t stream) {
    const float* rgb     = (const float*)d_in[0];
    const float* tgt     = (const float*)d_in[1];
    const float* opacity = (const float*)d_in[2];
    const float* grad    = (const float*)d_in[3];
    const float* ws      = (const float*)d_in[4];
    const float* deltas  = (const float*)d_in[5];
    const float* ts      = (const float*)d_in[6];
    const int*   rays_a  = (const int*)d_in[7];
    float* out      = (float*)d_out;
    float* partials = (float*)d_ws;

    nerf_main_kernel<<<NB, 256, 0, stream>>>(rgb, tgt, opacity, grad, ws,
                                             deltas, ts, rays_a, out, partials);
    nerf_final_kernel<<<1, 1024, 0, stream>>>(partials, out);
}